// Round 2
// baseline (447.722 us; speedup 1.0000x reference)
//
#include <hip/hip_runtime.h>
#include <stdint.h>

// Problem constants
#define B_   8
#define C_   256
#define N_   16384   // 128*128 spatial

typedef __attribute__((ext_vector_type(8))) short bf16x8;
typedef __attribute__((ext_vector_type(4))) float f32x4;

__device__ inline float bf2f(unsigned short h) {
    return __uint_as_float(((unsigned)h) << 16);
}
__device__ inline unsigned short f2bf(float f) {
    unsigned u = __float_as_uint(f);
    u += 0x7FFF + ((u >> 16) & 1);   // round-to-nearest-even
    return (unsigned short)(u >> 16);
}

// async global->LDS, 16B per lane. LDS dest = wave-uniform base + lane*16.
__device__ inline void gl_lds16(const void* g, void* l) {
    __builtin_amdgcn_global_load_lds(
        reinterpret_cast<const __attribute__((address_space(1))) unsigned int*>(
            reinterpret_cast<uintptr_t>(g)),
        reinterpret_cast<__attribute__((address_space(3))) unsigned int*>(
            reinterpret_cast<uintptr_t>(l)),
        16, 0, 0);
}

__device__ inline f32x4 mfma16(bf16x8 a, bf16x8 b, f32x4 c) {
    return __builtin_amdgcn_mfma_f32_16x16x32_bf16(a, b, c, 0, 0, 0);
}

// ---------------------------------------------------------------------------
// K1: x [B,C,N] fp32  ->  xT [B,N,C] bf16   (64x64 tiles through LDS)
// ---------------------------------------------------------------------------
__global__ __launch_bounds__(256) void k1_transpose(const float* __restrict__ x,
                                                    unsigned short* __restrict__ xT) {
    __shared__ unsigned short tile[64][65];
    const int b = blockIdx.z, c0 = blockIdx.y * 64, n0 = blockIdx.x * 64;
    const float* xb = x + (size_t)b * C_ * N_;
    const int t = threadIdx.x;
    const int tr = t >> 4, tc4 = (t & 15) * 4;
#pragma unroll
    for (int p = 0; p < 4; p++) {
        const int i = p * 16 + tr;   // c index
        const float4 v = *(const float4*)(xb + (size_t)(c0 + i) * N_ + n0 + tc4);
        tile[i][tc4 + 0] = f2bf(v.x);
        tile[i][tc4 + 1] = f2bf(v.y);
        tile[i][tc4 + 2] = f2bf(v.z);
        tile[i][tc4 + 3] = f2bf(v.w);
    }
    __syncthreads();
    unsigned short* xTb = xT + (size_t)b * N_ * C_;
#pragma unroll
    for (int p = 0; p < 4; p++) {
        const int jj = p * 16 + tr;  // n index
        ushort4 o;
        o.x = tile[tc4 + 0][jj];
        o.y = tile[tc4 + 1][jj];
        o.z = tile[tc4 + 2][jj];
        o.w = tile[tc4 + 3][jj];
        *(ushort4*)(xTb + (size_t)(n0 + jj) * C_ + c0 + tc4) = o;
    }
}

// ---------------------------------------------------------------------------
// K1b: convert w_qkv -> bf16 (blocks 0..191), block 192 computes BN constants
// ---------------------------------------------------------------------------
__global__ __launch_bounds__(256) void k1b_setup(const float* __restrict__ wqkv,
                                                 const float* __restrict__ gamma,
                                                 const float* __restrict__ beta,
                                                 const float* __restrict__ rmean,
                                                 const float* __restrict__ rvar,
                                                 unsigned short* __restrict__ wqkv_bf,
                                                 float* __restrict__ inv,
                                                 float* __restrict__ b2) {
    const int t = threadIdx.x;
    if (blockIdx.x < 192) {
        const int base = blockIdx.x * 1024 + t * 4;
        const float4 v = *(const float4*)(wqkv + base);
        ushort4 o;
        o.x = f2bf(v.x); o.y = f2bf(v.y); o.z = f2bf(v.z); o.w = f2bf(v.w);
        *(ushort4*)(wqkv_bf + base) = o;
    } else {
        const float iv = gamma[t] * rsqrtf(rvar[t] + 1e-5f);
        inv[t] = iv;
        b2[t]  = beta[t] - rmean[t] * iv;
    }
}

// ---------------------------------------------------------------------------
// K2: KV GEMM.  A = w_kv bf16 [512,256] (k-contig), B = xT (k-contig).
//     out rows 0..255 -> k logits, 256..511 -> v  (both [B,C,N] bf16)
// grid (128 n-tiles, 4 m-tiles, 8 batches), 256 thr
// ---------------------------------------------------------------------------
__global__ __launch_bounds__(256) void k2_kv(const unsigned short* __restrict__ Wkv,
                                             const unsigned short* __restrict__ xT,
                                             unsigned short* __restrict__ kL,
                                             unsigned short* __restrict__ v) {
    __shared__ __align__(16) unsigned short As[128 * 32];
    __shared__ __align__(16) unsigned short Bs[128 * 32];
    const int b  = blockIdx.z;
    const int m0 = blockIdx.y * 128;
    const int n0 = blockIdx.x * 128;
    const int t = threadIdx.x, wave = t >> 6, lane = t & 63;
    const int wm = wave >> 1, wn = wave & 1;

    const unsigned short* xTb = xT + (size_t)b * N_ * C_;

    const int ch1 = wave * 64 + lane, ch2 = ch1 + 256;
    const int r1 = ch1 >> 2, q1 = ch1 & 3;
    const int r2 = ch2 >> 2, q2 = ch2 & 3;
    // chunk bases in SHORT elements: chunk1 -> [0,2048), chunk2 -> [2048,4096)
    unsigned short* ldsA1 = As + wave * 512;
    unsigned short* ldsA2 = As + 2048 + wave * 512;
    unsigned short* ldsB1 = Bs + wave * 512;
    unsigned short* ldsB2 = Bs + 2048 + wave * 512;

    f32x4 acc[4][4];
#pragma unroll
    for (int i = 0; i < 4; i++)
#pragma unroll
        for (int j = 0; j < 4; j++)
#pragma unroll
            for (int r = 0; r < 4; r++) acc[i][j][r] = 0.f;

    const int fr = lane & 15;
    const int fk = (lane >> 4) * 8;

    for (int kk = 0; kk < 256; kk += 32) {
        __syncthreads();
        gl_lds16(Wkv + (size_t)(m0 + r1) * 256 + kk + q1 * 8, ldsA1);
        gl_lds16(Wkv + (size_t)(m0 + r2) * 256 + kk + q2 * 8, ldsA2);
        gl_lds16(xTb + (size_t)(n0 + r1) * 256 + kk + q1 * 8, ldsB1);
        gl_lds16(xTb + (size_t)(n0 + r2) * 256 + kk + q2 * 8, ldsB2);
        __syncthreads();
        bf16x8 af[4], bfv[4];
#pragma unroll
        for (int i = 0; i < 4; i++)
            af[i] = *(const bf16x8*)(As + (wm * 64 + i * 16 + fr) * 32 + fk);
#pragma unroll
        for (int j = 0; j < 4; j++)
            bfv[j] = *(const bf16x8*)(Bs + (wn * 64 + j * 16 + fr) * 32 + fk);
#pragma unroll
        for (int i = 0; i < 4; i++)
#pragma unroll
            for (int j = 0; j < 4; j++)
                acc[i][j] = mfma16(af[i], bfv[j], acc[i][j]);
    }

    const int col = lane & 15, rowq = (lane >> 4) * 4;
    unsigned short* outK = kL + (size_t)b * C_ * N_;
    unsigned short* outV = v  + (size_t)b * C_ * N_;
#pragma unroll
    for (int i = 0; i < 4; i++) {
        const int gm = m0 + wm * 64 + i * 16 + rowq;
#pragma unroll
        for (int j = 0; j < 4; j++) {
            const int gn = n0 + wn * 64 + j * 16 + col;
#pragma unroll
            for (int r = 0; r < 4; r++) {
                const int m = gm + r;
                const unsigned short hv = f2bf(acc[i][j][r]);
                if (m < 256) outK[(size_t)m * N_ + gn] = hv;
                else         outV[(size_t)(m - 256) * N_ + gn] = hv;
            }
        }
    }
}

// ---------------------------------------------------------------------------
// K3: per (b,c) row of k logits: rmax = max, rsum = sum(exp(x-max)). grid 2048
// ---------------------------------------------------------------------------
__global__ __launch_bounds__(256) void k3_stats(const unsigned short* __restrict__ kL,
                                                float* __restrict__ rmax,
                                                float* __restrict__ rsum) {
    const size_t rowbase = (size_t)blockIdx.x * N_;
    const int t = threadIdx.x;
    uint4 d[8];
#pragma unroll
    for (int i = 0; i < 8; i++)
        d[i] = *(const uint4*)(kL + rowbase + (size_t)(i * 256 + t) * 8);
    float m = -3.4e38f;
#pragma unroll
    for (int i = 0; i < 8; i++) {
        const unsigned short* p = (const unsigned short*)&d[i];
#pragma unroll
        for (int e = 0; e < 8; e++) m = fmaxf(m, bf2f(p[e]));
    }
#pragma unroll
    for (int o = 1; o < 64; o <<= 1) m = fmaxf(m, __shfl_xor(m, o, 64));
    __shared__ float red[4];
    __shared__ float red2[4];
    if ((t & 63) == 0) red[t >> 6] = m;
    __syncthreads();
    m = fmaxf(fmaxf(red[0], red[1]), fmaxf(red[2], red[3]));
    float s = 0.f;
#pragma unroll
    for (int i = 0; i < 8; i++) {
        const unsigned short* p = (const unsigned short*)&d[i];
#pragma unroll
        for (int e = 0; e < 8; e++) s += __expf(bf2f(p[e]) - m);
    }
#pragma unroll
    for (int o = 1; o < 64; o <<= 1) s += __shfl_xor(s, o, 64);
    if ((t & 63) == 0) red2[t >> 6] = s;
    __syncthreads();
    if (t == 0) {
        rmax[blockIdx.x] = m;
        rsum[blockIdx.x] = red2[0] + red2[1] + red2[2] + red2[3];
    }
}

// ---------------------------------------------------------------------------
// K4: ctx_raw[b,c,d] += sum_n exp(k[c,n]-max_c) * v[d,n].  Split-K over n
//     (8 chunks of 2048), fp32 atomicAdd.  A staged via registers (exp),
//     B via global_load_lds.   grid (2,2, B*8)
// ---------------------------------------------------------------------------
__global__ __launch_bounds__(256) void k4_ctx(const unsigned short* __restrict__ kL,
                                              const unsigned short* __restrict__ v,
                                              const float* __restrict__ rmax,
                                              float* __restrict__ ctx) {
    __shared__ __align__(16) unsigned short As[128 * 32];
    __shared__ __align__(16) unsigned short Bs[128 * 32];
    const int bz = blockIdx.z;
    const int b = bz >> 3, s = bz & 7;
    const int m0 = blockIdx.y * 128;   // c rows
    const int n0 = blockIdx.x * 128;   // d rows
    const int t = threadIdx.x, wave = t >> 6, lane = t & 63;
    const int wm = wave >> 1, wn = wave & 1;

    const unsigned short* kb = kL + (size_t)b * C_ * N_;
    const unsigned short* vb = v  + (size_t)b * C_ * N_;

    const int ch1 = wave * 64 + lane, ch2 = ch1 + 256;
    const int r1 = ch1 >> 2, q1 = ch1 & 3;
    const int r2 = ch2 >> 2, q2 = ch2 & 3;
    const float mx1 = rmax[b * 256 + m0 + r1];
    const float mx2 = rmax[b * 256 + m0 + r2];
    unsigned short* ldsB1 = Bs + wave * 512;
    unsigned short* ldsB2 = Bs + 2048 + wave * 512;

    f32x4 acc[4][4];
#pragma unroll
    for (int i = 0; i < 4; i++)
#pragma unroll
        for (int j = 0; j < 4; j++)
#pragma unroll
            for (int r = 0; r < 4; r++) acc[i][j][r] = 0.f;

    const int fr = lane & 15;
    const int fk = (lane >> 4) * 8;
    const int kbase = s * 2048;

    for (int kk = kbase; kk < kbase + 2048; kk += 32) {
        __syncthreads();
        gl_lds16(vb + (size_t)(n0 + r1) * N_ + kk + q1 * 8, ldsB1);
        gl_lds16(vb + (size_t)(n0 + r2) * N_ + kk + q2 * 8, ldsB2);
        const uint4 a1 = *(const uint4*)(kb + (size_t)(m0 + r1) * N_ + kk + q1 * 8);
        const uint4 a2 = *(const uint4*)(kb + (size_t)(m0 + r2) * N_ + kk + q2 * 8);
        uint4 e1, e2;
        {
            const unsigned short* p = (const unsigned short*)&a1;
            unsigned short* o = (unsigned short*)&e1;
#pragma unroll
            for (int e = 0; e < 8; e++) o[e] = f2bf(__expf(bf2f(p[e]) - mx1));
        }
        {
            const unsigned short* p = (const unsigned short*)&a2;
            unsigned short* o = (unsigned short*)&e2;
#pragma unroll
            for (int e = 0; e < 8; e++) o[e] = f2bf(__expf(bf2f(p[e]) - mx2));
        }
        *(uint4*)(As + r1 * 32 + q1 * 8) = e1;
        *(uint4*)(As + r2 * 32 + q2 * 8) = e2;
        __syncthreads();
        bf16x8 af[4], bfv[4];
#pragma unroll
        for (int i = 0; i < 4; i++)
            af[i] = *(const bf16x8*)(As + (wm * 64 + i * 16 + fr) * 32 + fk);
#pragma unroll
        for (int j = 0; j < 4; j++)
            bfv[j] = *(const bf16x8*)(Bs + (wn * 64 + j * 16 + fr) * 32 + fk);
#pragma unroll
        for (int i = 0; i < 4; i++)
#pragma unroll
            for (int j = 0; j < 4; j++)
                acc[i][j] = mfma16(af[i], bfv[j], acc[i][j]);
    }

    float* cb = ctx + (size_t)b * C_ * C_;
    const int col = lane & 15, rowq = (lane >> 4) * 4;
#pragma unroll
    for (int i = 0; i < 4; i++) {
        const int gc = m0 + wm * 64 + i * 16 + rowq;
#pragma unroll
        for (int j = 0; j < 4; j++) {
            const int gd = n0 + wn * 64 + j * 16 + col;
#pragma unroll
            for (int r = 0; r < 4; r++)
                atomicAdd(&cb[(size_t)(gc + r) * C_ + gd], acc[i][j][r]);
        }
    }
}

// ---------------------------------------------------------------------------
// K5a: T[b,o,c] = (sum_d Wp[o,d]*ctx[b,c,d]) / rsum[b,c]   (fp32 tiled)
// grid (4,4,8) : 64x64 tiles
// ---------------------------------------------------------------------------
__global__ __launch_bounds__(256) void k5a_T(const float* __restrict__ Wp,
                                             const float* __restrict__ ctx,
                                             const float* __restrict__ rsum,
                                             float* __restrict__ T) {
    __shared__ float Asm[64][65];
    __shared__ float Bsm[64][65];
    const int b = blockIdx.z;
    const int o0 = blockIdx.y * 64, c0 = blockIdx.x * 64;
    const int t = threadIdx.x;
    const int tm = t >> 4, tn = t & 15;
    const int lc4 = tn * 4;
    float acc[4][4] = {};
    const float* cb = ctx + (size_t)b * C_ * C_;
    for (int kk = 0; kk < 256; kk += 64) {
        __syncthreads();
#pragma unroll
        for (int p = 0; p < 4; p++) {
            const int r = p * 16 + tm;
            const float4 av = *(const float4*)(Wp + (size_t)(o0 + r) * C_ + kk + lc4);
            Asm[r][lc4] = av.x; Asm[r][lc4 + 1] = av.y; Asm[r][lc4 + 2] = av.z; Asm[r][lc4 + 3] = av.w;
            const float4 bv = *(const float4*)(cb + (size_t)(c0 + r) * C_ + kk + lc4);
            Bsm[r][lc4] = bv.x; Bsm[r][lc4 + 1] = bv.y; Bsm[r][lc4 + 2] = bv.z; Bsm[r][lc4 + 3] = bv.w;
        }
        __syncthreads();
        for (int k = 0; k < 64; k++) {
            float a_[4], b_[4];
#pragma unroll
            for (int i = 0; i < 4; i++) a_[i] = Asm[tm * 4 + i][k];
#pragma unroll
            for (int j = 0; j < 4; j++) b_[j] = Bsm[tn * 4 + j][k];
#pragma unroll
            for (int i = 0; i < 4; i++)
#pragma unroll
                for (int j = 0; j < 4; j++) acc[i][j] += a_[i] * b_[j];
        }
    }
    float isv[4];
#pragma unroll
    for (int j = 0; j < 4; j++) isv[j] = 1.f / rsum[b * 256 + c0 + tn * 4 + j];
#pragma unroll
    for (int i = 0; i < 4; i++)
#pragma unroll
        for (int j = 0; j < 4; j++)
            T[((size_t)b * C_ + o0 + tm * 4 + i) * C_ + c0 + tn * 4 + j] = acc[i][j] * isv[j];
}

// ---------------------------------------------------------------------------
// K5b: G[b,o,j] = inv[o] * sum_c T[b,o,c]*Wq[c,j]   -> bf16  (fp32 tiled)
// grid (4,4,8)
// ---------------------------------------------------------------------------
__global__ __launch_bounds__(256) void k5b_G(const float* __restrict__ Tm,
                                             const float* __restrict__ Wq,
                                             const float* __restrict__ inv,
                                             unsigned short* __restrict__ G) {
    __shared__ float Asm[64][65];   // T rows o, cols c (k)
    __shared__ float Bsm[64][65];   // Wq rows c (k), cols j
    const int b = blockIdx.z;
    const int o0 = blockIdx.y * 64, j0 = blockIdx.x * 64;
    const int t = threadIdx.x;
    const int tm = t >> 4, tn = t & 15;
    const int lc4 = tn * 4;
    float acc[4][4] = {};
    const float* Tb = Tm + (size_t)b * C_ * C_;
    for (int kk = 0; kk < 256; kk += 64) {
        __syncthreads();
#pragma unroll
        for (int p = 0; p < 4; p++) {
            const int r = p * 16 + tm;
            const float4 av = *(const float4*)(Tb + (size_t)(o0 + r) * C_ + kk + lc4);
            Asm[r][lc4] = av.x; Asm[r][lc4 + 1] = av.y; Asm[r][lc4 + 2] = av.z; Asm[r][lc4 + 3] = av.w;
            const float4 bv = *(const float4*)(Wq + (size_t)(kk + r) * C_ + j0 + lc4);
            Bsm[r][lc4] = bv.x; Bsm[r][lc4 + 1] = bv.y; Bsm[r][lc4 + 2] = bv.z; Bsm[r][lc4 + 3] = bv.w;
        }
        __syncthreads();
        for (int k = 0; k < 64; k++) {
            float a_[4], b_[4];
#pragma unroll
            for (int i = 0; i < 4; i++) a_[i] = Asm[tm * 4 + i][k];
#pragma unroll
            for (int j = 0; j < 4; j++) b_[j] = Bsm[k][tn * 4 + j];
#pragma unroll
            for (int i = 0; i < 4; i++)
#pragma unroll
                for (int j = 0; j < 4; j++) acc[i][j] += a_[i] * b_[j];
        }
    }
#pragma unroll
    for (int i = 0; i < 4; i++) {
        const float iv = inv[o0 + tm * 4 + i];
#pragma unroll
        for (int j = 0; j < 4; j++)
            G[((size_t)b * C_ + o0 + tm * 4 + i) * C_ + j0 + tn * 4 + j] = f2bf(acc[i][j] * iv);
    }
}

// ---------------------------------------------------------------------------
// K6: out[b,o,n] = relu( sum_j G[b,o,j]*xT[b,n,j] + b2[o] )  fp32 out
// grid (128 n-tiles, 2 m-tiles, 8)
// ---------------------------------------------------------------------------
__global__ __launch_bounds__(256) void k6_out(const unsigned short* __restrict__ G,
                                              const unsigned short* __restrict__ xT,
                                              const float* __restrict__ b2,
                                              float* __restrict__ out) {
    __shared__ __align__(16) unsigned short As[128 * 32];
    __shared__ __align__(16) unsigned short Bs[128 * 32];
    const int b  = blockIdx.z;
    const int m0 = blockIdx.y * 128;
    const int n0 = blockIdx.x * 128;
    const int t = threadIdx.x, wave = t >> 6, lane = t & 63;
    const int wm = wave >> 1, wn = wave & 1;

    const unsigned short* Gb  = G  + (size_t)b * C_ * C_;
    const unsigned short* xTb = xT + (size_t)b * N_ * C_;

    const int ch1 = wave * 64 + lane, ch2 = ch1 + 256;
    const int r1 = ch1 >> 2, q1 = ch1 & 3;
    const int r2 = ch2 >> 2, q2 = ch2 & 3;
    unsigned short* ldsA1 = As + wave * 512;
    unsigned short* ldsA2 = As + 2048 + wave * 512;
    unsigned short* ldsB1 = Bs + wave * 512;
    unsigned short* ldsB2 = Bs + 2048 + wave * 512;

    f32x4 acc[4][4];
#pragma unroll
    for (int i = 0; i < 4; i++)
#pragma unroll
        for (int j = 0; j < 4; j++)
#pragma unroll
            for (int r = 0; r < 4; r++) acc[i][j][r] = 0.f;

    const int fr = lane & 15;
    const int fk = (lane >> 4) * 8;

    for (int kk = 0; kk < 256; kk += 32) {
        __syncthreads();
        gl_lds16(Gb  + (size_t)(m0 + r1) * 256 + kk + q1 * 8, ldsA1);
        gl_lds16(Gb  + (size_t)(m0 + r2) * 256 + kk + q2 * 8, ldsA2);
        gl_lds16(xTb + (size_t)(n0 + r1) * 256 + kk + q1 * 8, ldsB1);
        gl_lds16(xTb + (size_t)(n0 + r2) * 256 + kk + q2 * 8, ldsB2);
        __syncthreads();
        bf16x8 af[4], bfv[4];
#pragma unroll
        for (int i = 0; i < 4; i++)
            af[i] = *(const bf16x8*)(As + (wm * 64 + i * 16 + fr) * 32 + fk);
#pragma unroll
        for (int j = 0; j < 4; j++)
            bfv[j] = *(const bf16x8*)(Bs + (wn * 64 + j * 16 + fr) * 32 + fk);
#pragma unroll
        for (int i = 0; i < 4; i++)
#pragma unroll
            for (int j = 0; j < 4; j++)
                acc[i][j] = mfma16(af[i], bfv[j], acc[i][j]);
    }

    const int col = lane & 15, rowq = (lane >> 4) * 4;
    float* ob = out + (size_t)b * C_ * N_;
#pragma unroll
    for (int i = 0; i < 4; i++) {
        const int gm = m0 + wm * 64 + i * 16 + rowq;
#pragma unroll
        for (int j = 0; j < 4; j++) {
            const int gn = n0 + wn * 64 + j * 16 + col;
#pragma unroll
            for (int r = 0; r < 4; r++) {
                const float val = fmaxf(acc[i][j][r] + b2[gm + r], 0.f);
                ob[(size_t)(gm + r) * N_ + gn] = val;
            }
        }
    }
}

// ---------------------------------------------------------------------------
extern "C" void kernel_launch(void* const* d_in, const int* in_sizes, int n_in,
                              void* d_out, int out_size, void* d_ws, size_t ws_size,
                              hipStream_t stream) {
    const float* x     = (const float*)d_in[0];
    const float* wqkv  = (const float*)d_in[1];
    const float* wproj = (const float*)d_in[2];
    const float* gamma = (const float*)d_in[3];
    const float* beta  = (const float*)d_in[4];
    const float* rmean = (const float*)d_in[5];
    const float* rvar  = (const float*)d_in[6];
    float* out = (float*)d_out;

    char* ws = (char*)d_ws;
    size_t off = 0;
    auto alloc = [&](size_t bytes) {
        void* p = ws + off;
        off += (bytes + 255) & ~(size_t)255;
        return p;
    };
    unsigned short* xT      = (unsigned short*)alloc((size_t)B_ * N_ * C_ * 2);  // 64 MiB
    unsigned short* kL      = (unsigned short*)alloc((size_t)B_ * C_ * N_ * 2);  // 64 MiB
    unsigned short* vv      = (unsigned short*)alloc((size_t)B_ * C_ * N_ * 2);  // 64 MiB
    unsigned short* wqkv_bf = (unsigned short*)alloc((size_t)768 * 256 * 2);
    float* rmax = (float*)alloc(2048 * 4);
    float* rsum = (float*)alloc(2048 * 4);
    float* invp = (float*)alloc(256 * 4);
    float* b2p  = (float*)alloc(256 * 4);
    float* ctx  = (float*)alloc((size_t)B_ * C_ * C_ * 4);   // 2 MiB
    float* Tm   = (float*)alloc((size_t)B_ * C_ * C_ * 4);   // 2 MiB
    unsigned short* G = (unsigned short*)alloc((size_t)B_ * C_ * C_ * 2);

    hipLaunchKernelGGL(k1_transpose, dim3(256, 4, 8), dim3(256), 0, stream, x, xT);
    hipLaunchKernelGGL(k1b_setup, dim3(193), dim3(256), 0, stream,
                       wqkv, gamma, beta, rmean, rvar, wqkv_bf, invp, b2p);
    hipLaunchKernelGGL(k2_kv, dim3(128, 4, 8), dim3(256), 0, stream,
                       wqkv_bf + 256 * 256, xT, kL, vv);
    hipLaunchKernelGGL(k3_stats, dim3(2048), dim3(256), 0, stream, kL, rmax, rsum);
    hipMemsetAsync(ctx, 0, (size_t)B_ * C_ * C_ * 4, stream);
    hipLaunchKernelGGL(k4_ctx, dim3(2, 2, 64), dim3(256), 0, stream, kL, vv, rmax, ctx);
    hipLaunchKernelGGL(k5a_T, dim3(4, 4, 8), dim3(256), 0, stream, wproj, ctx, rsum, Tm);
    hipLaunchKernelGGL(k5b_G, dim3(4, 4, 8), dim3(256), 0, stream, Tm, wqkv, invp, G);
    hipLaunchKernelGGL(k6_out, dim3(128, 2, 8), dim3(256), 0, stream, G, xT, b2p, out);
}